// Round 18
// baseline (132.908 us; speedup 1.0000x reference)
//
#include <hip/hip_runtime.h>

typedef _Float16 f16;
typedef _Float16 f16x8 __attribute__((ext_vector_type(8)));
typedef _Float16 f16x4 __attribute__((ext_vector_type(4)));
typedef float f32x4 __attribute__((ext_vector_type(4)));

__device__ __forceinline__ float rcpf(float x) { return __builtin_amdgcn_rcpf(x); }

__device__ __forceinline__ void gload_lds16(const void* g, void* l) {
  __builtin_amdgcn_global_load_lds(
      (const __attribute__((address_space(1))) void*)g,
      (__attribute__((address_space(3))) void*)l, 16, 0, 0);
}

// ---------------- kernel 1: weight convert -> FRAGMENT-ORDERED layout ------
// Wt'[(nt*3+w)*8+kt][kq][ni][rl][8 halfs]
__global__ void __launch_bounds__(256) cvt_w(const float* __restrict__ Wr,
                                             const float* __restrict__ Wz,
                                             const float* __restrict__ Wh,
                                             f16* __restrict__ out) {
  int o = blockIdx.x * 256 + threadIdx.x;        // < 49152
  int rl = o & 15, ni = (o >> 4) & 3, kq = (o >> 6) & 3, kt = (o >> 8) & 7;
  int wnt = o >> 11;
  int w = wnt % 3, nt = wnt / 3;
  int n = nt * 64 + ni * 16 + rl;
  int k0 = kt * 32 + kq * 8;
  const float* W = (w == 0) ? Wr : ((w == 1) ? Wz : Wh);
  f16x8 v;
#pragma unroll
  for (int e = 0; e < 8; ++e) v[e] = (f16)W[(size_t)(k0 + e) * 512 + n];
  *(f16x8*)(out + (size_t)o * 8) = v;
}

// ---------------- kernel 2: producer/consumer fused GEMM + scan ------------
// R17 base (fused=96us, proven no-spill) + cvt_x FUSED AWAY:
// A is staged per phase as RAW F32 from x (32KB: 32 rows x 1KB) via
// global_load_lds with XOR-swizzled per-lane SOURCE (linear dest, rule #21);
// producers ds_read the f32 pair with the same XOR and convert to f16
// fragments in-register (~200 VALU/wave-phase, hidden under MFMA).
// Kills the separate 201MB cvt_x pass + one dispatch.
// LDS: P dbuf 48KB + A f32 32KB = 80KB -> 2 blocks/CU unchanged.
__global__ void __launch_bounds__(512, 4) brc_fused(
    const float* __restrict__ X32, const f16* __restrict__ Bf,
    const float* __restrict__ h0, const float* __restrict__ mr,
    const float* __restrict__ mz, const float* __restrict__ br,
    const float* __restrict__ bz, float* __restrict__ out) {
  __shared__ __align__(16) f16 Pl[2][12288];     // [buf][w3*4096+tg*1024+hl*8+t7]
  __shared__ __align__(16) float Alf[8192];      // 32KB: 32 t-rows x 256 f32
  const int tid = threadIdx.x;
  const int wid = tid >> 6, lane = tid & 63;
  const int bid = blockIdx.x;
  const int lid = (bid & 7) * 64 + (bid >> 3);   // bijective XCD swizzle
  const int b = lid >> 2, hs = lid & 3;          // 4 hs-blocks of a b adjacent

  // ---- producer constants (waves 0..5) ----
  const int w3 = wid >> 1, hh = wid & 1;
  const int nt = hs * 2 + hh;
  const char* Bp = (const char*)Bf + (lane >> 4) * 1024 + (lane & 15) * 16 +
                   (size_t)(nt * 3 + w3) * 32768;
  const int col = lane & 15, rbase = (lane >> 4) * 4;
  const char* Xb = (const char*)(X32 + (size_t)b * 131072);

  // ---- consumer state (waves 6,7): chain c = tid & 127 ----
  const int c = tid & 127;
  const int hg = hs * 128 + c;
  float h = h0[(size_t)b * 512 + hg];
  const float mrc = 2.0f * mr[hg], mzc = -mz[hg];
  const float br2 = 2.0f * br[hg], nbz = -bz[hg];

  // stage phase q's A slice: rows t = q*32+j (j=0..31), 1KB each, 6 waves
  // round-robin. Linear LDS dest; XOR-swizzle applied on the per-lane SOURCE
  // byte within the row so reads can use the same XOR (bank-spread).
#define STAGEA(q)                                                             \
  do {                                                                        \
    for (int j = wid; j < 32; j += 6)                                         \
      gload_lds16(Xb + (size_t)((q) * 32 + j) * 1024 +                        \
                      ((lane * 16) ^ ((j & 7) << 4)),                         \
                  (char*)Alf + j * 1024);                                     \
  } while (0)

  auto gemm_phase = [&](int q) {
    f16* Pb = Pl[q & 1];
    f32x4 acc[2][4] = {};
    const int rl = lane & 15, kq = lane >> 4;
#pragma unroll
    for (int kt = 0; kt < 8; ++kt) {
      f16x8 a[2], bfr[4];
#pragma unroll
      for (int mi = 0; mi < 2; ++mi) {
        int row = mi * 16 + rl;
        int off = kt * 128 + kq * 32;            // byte offset of 8 f32 in row
        int s = (row & 7) << 4;
        const char* base = (const char*)Alf + row * 1024;
        f32x4 lo = *(const f32x4*)(base + ((off) ^ s));
        f32x4 hi = *(const f32x4*)(base + ((off + 16) ^ s));
#pragma unroll
        for (int e = 0; e < 4; ++e) {
          a[mi][e] = (f16)lo[e];
          a[mi][4 + e] = (f16)hi[e];
        }
      }
#pragma unroll
      for (int ni = 0; ni < 4; ++ni)
        bfr[ni] = *(const f16x8*)(Bp + (size_t)kt * 4096 + ni * 256);
#pragma unroll
      for (int mi = 0; mi < 2; ++mi)
#pragma unroll
        for (int ni = 0; ni < 4; ++ni)
          acc[mi][ni] = __builtin_amdgcn_mfma_f32_16x16x32_f16(
              a[mi], bfr[ni], acc[mi][ni], 0, 0, 0);
    }
#pragma unroll
    for (int mi = 0; mi < 2; ++mi) {
      int tl = mi * 16 + rbase;                  // 0..31
#pragma unroll
      for (int ni = 0; ni < 4; ++ni) {
        int hl = hh * 64 + ni * 16 + col;        // 0..127
        f16x4 v;
#pragma unroll
        for (int r = 0; r < 4; ++r) v[r] = (f16)acc[mi][ni][r];
        *(f16x4*)&Pb[w3 * 4096 + (tl >> 3) * 1024 + hl * 8 + (tl & 7)] = v;
      }
    }
  };

  if (wid < 6) STAGEA(0);
  __syncthreads();                               // A0 landed (vmcnt drain)
  if (wid < 6) gemm_phase(0);                    // prologue

  for (int p = 0; p < 16; ++p) {
    __syncthreads();                             // P[p&1] ready; A[p] dead
    if (wid < 6 && p + 1 < 16) STAGEA(p + 1);
    __syncthreads();                             // A[p+1] landed
    if (wid < 6) {
      if (p + 1 < 16) gemm_phase(p + 1);
    } else {
      const f16* Pr_ = &Pl[p & 1][c * 8];
      const f16* Pz_ = Pr_ + 4096;
      const f16* Ph_ = Pr_ + 8192;
      float* opm = out + ((size_t)b * 512 + p * 32) * 512 + hg;
#pragma unroll
      for (int g = 0; g < 4; ++g) {
        f16x8 R  = *(const f16x8*)(Pr_ + g * 1024);
        f16x8 Z  = *(const f16x8*)(Pz_ + g * 1024);
        f16x8 Hh = *(const f16x8*)(Ph_ + g * 1024);
#pragma unroll
        for (int j = 0; j < 8; ++j) {
          float prs = fmaf((float)R[j], 2.0f, br2);
          float pzs = fmaf((float)Z[j], -1.0f, nbz);
          float ph2 = (float)Hh[j] * 2.0f;
          float er = __expf(fmaf(h, mrc, prs));
          float rr = fmaf(-2.0f, rcpf(er + 1.0f), 2.0f);
          float ez = __expf(fmaf(h, mzc, pzs));
          float zz = rcpf(1.0f + ez);
          float ec = __expf(fmaf(rr, h + h, ph2));
          float cd = fmaf(-2.0f, rcpf(ec + 1.0f), 1.0f);
          h = fmaf(zz, h - cd, cd);
          __builtin_nontemporal_store(h, opm + (size_t)(g * 8 + j) * 512);
        }
      }
    }
  }
#undef STAGEA
}

// ---------------- launch ----------------
extern "C" void kernel_launch(void* const* d_in, const int* in_sizes, int n_in,
                              void* d_out, int out_size, void* d_ws, size_t ws_size,
                              hipStream_t stream) {
  const float* x  = (const float*)d_in[0];
  const float* h0 = (const float*)d_in[1];
  const float* kr = (const float*)d_in[2];
  const float* kz = (const float*)d_in[3];
  const float* kh = (const float*)d_in[4];
  const float* mr = (const float*)d_in[5];
  const float* mz = (const float*)d_in[6];
  const float* br = (const float*)d_in[7];
  const float* bz = (const float*)d_in[8];
  float* out = (float*)d_out;

  f16* Bf = (f16*)d_ws;                 // 393216 halfs = 786 KB

  cvt_w<<<192, 256, 0, stream>>>(kr, kz, kh, Bf);
  brc_fused<<<512, 512, 0, stream>>>(x, Bf, h0, mr, mz, br, bz, out);
}

// Round 19
// 122.579 us; speedup vs baseline: 1.0843x; 1.0843x over previous
//
#include <hip/hip_runtime.h>

typedef _Float16 f16;
typedef _Float16 f16x8 __attribute__((ext_vector_type(8)));
typedef _Float16 f16x4 __attribute__((ext_vector_type(4)));
typedef float f32x4 __attribute__((ext_vector_type(4)));

__device__ __forceinline__ float rcpf(float x) { return __builtin_amdgcn_rcpf(x); }

__device__ __forceinline__ void gload_lds16(const void* g, void* l) {
  __builtin_amdgcn_global_load_lds(
      (const __attribute__((address_space(1))) void*)g,
      (__attribute__((address_space(3))) void*)l, 16, 0, 0);
}

// ---------------- kernel 1: weight convert -> FRAGMENT-ORDERED layout ------
// Wt'[(nt*3+w)*8+kt][kq][ni][rl][8 halfs]   (nt = 64-wide h tile, 0..7)
__global__ void __launch_bounds__(256) cvt_w(const float* __restrict__ Wr,
                                             const float* __restrict__ Wz,
                                             const float* __restrict__ Wh,
                                             f16* __restrict__ out) {
  int o = blockIdx.x * 256 + threadIdx.x;        // < 49152
  int rl = o & 15, ni = (o >> 4) & 3, kq = (o >> 6) & 3, kt = (o >> 8) & 7;
  int wnt = o >> 11;
  int w = wnt % 3, nt = wnt / 3;
  int n = nt * 64 + ni * 16 + rl;
  int k0 = kt * 32 + kq * 8;
  const float* W = (w == 0) ? Wr : ((w == 1) ? Wz : Wh);
  f16x8 v;
#pragma unroll
  for (int e = 0; e < 8; ++e) v[e] = (f16)W[(size_t)(k0 + e) * 512 + n];
  *(f16x8*)(out + (size_t)o * 8) = v;
}

// ---------------- kernel 2: x convert f32->f16, FRAGMENT-ORDERED -----------
// Xf'[m16*8+kt][kq][rl][8 halfs]
__global__ void __launch_bounds__(256) cvt_x(const float* __restrict__ in,
                                             f16* __restrict__ out) {
  int o = blockIdx.x * 256 + threadIdx.x;        // < 2097152
  int rl = o & 15, kq = (o >> 4) & 3, kt = (o >> 6) & 7, m16 = o >> 9;
  const float* src = in + (size_t)(m16 * 16 + rl) * 256 + kt * 32 + kq * 8;
  f16x8 v;
#pragma unroll
  for (int e = 0; e < 8; ++e) v[e] = (f16)src[e];
  *(f16x8*)(out + (size_t)o * 8) = v;
}

// ---------------- kernel 3: producer/consumer fused GEMM + scan ------------
// R15 shape (256 thr, granted 112 VGPR) + R17's A-through-LDS (the two
// independently-proven port levers, combined):
// Block = (b, hs: 64-wide h slice), grid 1024, 4 waves.
// Waves 0..2 (producers): one WEIGHT each, tile 64t x 64h (acc[4][4]);
//   B from global (32KB/wave/phase, amortized over 64 t-rows = half of the
//   32t-phase variants); A read via ds_read_b128 from a per-phase 32KB LDS
//   slice staged ONCE by global_load_lds (A off the L1 return port).
// Wave 3 (consumer): 64 chains, scans 64 t-steps of phase p from P buf p&1.
// L1-port bytes/CU: ~3MB (B only) vs R17's 6MB, R15's 6MB (A+B).
// LDS: P dbuf 48KB + A 32KB = 80KB -> 2 blocks/CU. 8 phases, 2 barriers each.
__global__ void __launch_bounds__(256) brc_fused(
    const f16* __restrict__ Af, const f16* __restrict__ Bf,
    const float* __restrict__ h0, const float* __restrict__ mr,
    const float* __restrict__ mz, const float* __restrict__ br,
    const float* __restrict__ bz, float* __restrict__ out) {
  __shared__ __align__(16) f16 Pl[2][12288];     // [buf][w*4096+tg*512+hl*8+t7]
  __shared__ __align__(16) f16 Al[16384];        // 32KB: phase A slice, frag order
  const int tid = threadIdx.x;
  const int wid = tid >> 6, lane = tid & 63;
  const int bid = blockIdx.x;
  const int lid = (bid & 7) * 128 + (bid >> 3);  // bijective XCD swizzle
  const int b = lid >> 3, hs = lid & 7;          // 8 hs-blocks of a b adjacent

  // ---- producer constants (waves 0..2): weight w3 = wid ----
  const int w3 = wid < 3 ? wid : 0;
  const char* Bp = (const char*)Bf + (lane >> 4) * 1024 + (lane & 15) * 16 +
                   (size_t)(hs * 3 + w3) * 32768;
  const int col = lane & 15, rbase = (lane >> 4) * 4;

  // ---- consumer state (wave 3): chain = lane ----
  float h = 0.f, mrc = 0.f, mzc = 0.f, br2 = 0.f, nbz = 0.f;
  if (wid == 3) {
    int hg = hs * 64 + lane;
    h = h0[(size_t)b * 512 + hg];
    mrc = 2.0f * mr[hg]; mzc = -mz[hg];
    br2 = 2.0f * br[hg]; nbz = -bz[hg];
  }

  // stage phase q's A slice: frags (b*32+q*4+mi)*8+kt = 32 contiguous 1KB
  // chunks; producer waves round-robin (11/11/10 chunks).
#define STAGEA(q)                                                             \
  do {                                                                        \
    const char* gsrc = (const char*)Af + ((size_t)(b * 32 + (q) * 4) * 8) * 1024; \
    for (int j = wid; j < 32; j += 3)                                         \
      gload_lds16(gsrc + (size_t)j * 1024 + lane * 16, (char*)Al + j * 1024); \
  } while (0)

  auto gemm_phase = [&](int q) {
    f16* Pb = Pl[q & 1];
    f32x4 acc[4][4] = {};
#pragma unroll
    for (int kt = 0; kt < 8; ++kt) {
      f16x8 a[4], bf[4];
#pragma unroll
      for (int mi = 0; mi < 4; ++mi)
        a[mi] = *(const f16x8*)((const char*)Al + (mi * 8 + kt) * 1024 + lane * 16);
#pragma unroll
      for (int ni = 0; ni < 4; ++ni)
        bf[ni] = *(const f16x8*)(Bp + (size_t)kt * 4096 + ni * 256);
#pragma unroll
      for (int mi = 0; mi < 4; ++mi)
#pragma unroll
        for (int ni = 0; ni < 4; ++ni)
          acc[mi][ni] = __builtin_amdgcn_mfma_f32_16x16x32_f16(
              a[mi], bf[ni], acc[mi][ni], 0, 0, 0);
    }
#pragma unroll
    for (int mi = 0; mi < 4; ++mi) {
      int tl = mi * 16 + rbase;                  // 0..63
#pragma unroll
      for (int ni = 0; ni < 4; ++ni) {
        int hl = ni * 16 + col;                  // 0..63
        f16x4 v;
#pragma unroll
        for (int r = 0; r < 4; ++r) v[r] = (f16)acc[mi][ni][r];
        *(f16x4*)&Pb[w3 * 4096 + (tl >> 3) * 512 + hl * 8 + (tl & 7)] = v;
      }
    }
  };

  if (wid < 3) STAGEA(0);
  __syncthreads();                               // A0 landed
  if (wid < 3) gemm_phase(0);                    // prologue

  for (int p = 0; p < 8; ++p) {
    __syncthreads();                             // P[p&1] ready; A[p] dead
    if (wid < 3 && p + 1 < 8) STAGEA(p + 1);
    __syncthreads();                             // A[p+1] landed
    if (wid < 3) {
      if (p + 1 < 8) gemm_phase(p + 1);
    } else {
      const f16* Pb = Pl[p & 1];
      float* opm = out + ((size_t)b * 512 + p * 64) * 512 + hs * 64 + lane;
#pragma unroll
      for (int tg = 0; tg < 8; ++tg) {
        f16x8 R  = *(const f16x8*)&Pb[tg * 512 + lane * 8];
        f16x8 Z  = *(const f16x8*)&Pb[4096 + tg * 512 + lane * 8];
        f16x8 Hh = *(const f16x8*)&Pb[8192 + tg * 512 + lane * 8];
#pragma unroll
        for (int j = 0; j < 8; ++j) {
          float prs = fmaf((float)R[j], 2.0f, br2);
          float pzs = fmaf((float)Z[j], -1.0f, nbz);
          float ph2 = (float)Hh[j] * 2.0f;
          float er = __expf(fmaf(h, mrc, prs));
          float rr = fmaf(-2.0f, rcpf(er + 1.0f), 2.0f);
          float ez = __expf(fmaf(h, mzc, pzs));
          float zz = rcpf(1.0f + ez);
          float ec = __expf(fmaf(rr, h + h, ph2));
          float cd = fmaf(-2.0f, rcpf(ec + 1.0f), 1.0f);
          h = fmaf(zz, h - cd, cd);
          __builtin_nontemporal_store(h, opm + (size_t)(tg * 8 + j) * 512);
        }
      }
    }
  }
#undef STAGEA
}

// ---------------- launch ----------------
extern "C" void kernel_launch(void* const* d_in, const int* in_sizes, int n_in,
                              void* d_out, int out_size, void* d_ws, size_t ws_size,
                              hipStream_t stream) {
  const float* x  = (const float*)d_in[0];
  const float* h0 = (const float*)d_in[1];
  const float* kr = (const float*)d_in[2];
  const float* kz = (const float*)d_in[3];
  const float* kh = (const float*)d_in[4];
  const float* mr = (const float*)d_in[5];
  const float* mz = (const float*)d_in[6];
  const float* br = (const float*)d_in[7];
  const float* bz = (const float*)d_in[8];
  float* out = (float*)d_out;

  f16* Bf = (f16*)d_ws;                 // 393216 halfs = 786 KB
  f16* Xf = Bf + 393216;                // 16.8M halfs = 33.5 MB

  cvt_w<<<192, 256, 0, stream>>>(kr, kz, kh, Bf);
  cvt_x<<<8192, 256, 0, stream>>>(x, Xf);
  brc_fused<<<1024, 256, 0, stream>>>(Xf, Bf, h0, mr, mz, br, bz, out);
}

// Round 20
// 121.852 us; speedup vs baseline: 1.0907x; 1.0060x over previous
//
#include <hip/hip_runtime.h>

typedef _Float16 f16;
typedef _Float16 f16x8 __attribute__((ext_vector_type(8)));
typedef _Float16 f16x4 __attribute__((ext_vector_type(4)));
typedef float f32x4 __attribute__((ext_vector_type(4)));

__device__ __forceinline__ float rcpf(float x) { return __builtin_amdgcn_rcpf(x); }

__device__ __forceinline__ void gload_lds16(const void* g, void* l) {
  __builtin_amdgcn_global_load_lds(
      (const __attribute__((address_space(1))) void*)g,
      (__attribute__((address_space(3))) void*)l, 16, 0, 0);
}

// ---------------- kernel 1: weight convert -> FRAGMENT-ORDERED layout ------
// Wt'[(nt*3+w)*8+kt][kq][ni][rl][8 halfs]   (nt = 64-wide h tile, 0..7)
__global__ void __launch_bounds__(256) cvt_w(const float* __restrict__ Wr,
                                             const float* __restrict__ Wz,
                                             const float* __restrict__ Wh,
                                             f16* __restrict__ out) {
  int o = blockIdx.x * 256 + threadIdx.x;        // < 49152
  int rl = o & 15, ni = (o >> 4) & 3, kq = (o >> 6) & 3, kt = (o >> 8) & 7;
  int wnt = o >> 11;
  int w = wnt % 3, nt = wnt / 3;
  int n = nt * 64 + ni * 16 + rl;
  int k0 = kt * 32 + kq * 8;
  const float* W = (w == 0) ? Wr : ((w == 1) ? Wz : Wh);
  f16x8 v;
#pragma unroll
  for (int e = 0; e < 8; ++e) v[e] = (f16)W[(size_t)(k0 + e) * 512 + n];
  *(f16x8*)(out + (size_t)o * 8) = v;
}

// ---------------- kernel 2: x convert f32->f16, FRAGMENT-ORDERED -----------
// Xf'[m16*8+kt][kq][rl][8 halfs]
__global__ void __launch_bounds__(256) cvt_x(const float* __restrict__ in,
                                             f16* __restrict__ out) {
  int o = blockIdx.x * 256 + threadIdx.x;        // < 2097152
  int rl = o & 15, kq = (o >> 4) & 3, kt = (o >> 6) & 7, m16 = o >> 9;
  const float* src = in + (size_t)(m16 * 16 + rl) * 256 + kt * 32 + kq * 8;
  f16x8 v;
#pragma unroll
  for (int e = 0; e < 8; ++e) v[e] = (f16)src[e];
  *(f16x8*)(out + (size_t)o * 8) = v;
}

// ---------------- kernel 3: producer/consumer fused GEMM + scan ------------
// R19 base + PERSISTENT-B-IN-REGISTERS:
// B is phase-invariant, so each producer preloads its whole B slice
// (8kt x 4ni x f16x8 = 128 VGPRs) ONCE; the phase loop then issues ZERO
// global loads -- just ds_read(A) + MFMA. __launch_bounds__(256,2) raises
// the VGPR cap to 256 (2 waves/SIMD = what 80KB LDS allows anyway);
// needed ~230. Discriminator: WRITE must stay exactly 131072 KB (no spill).
// Block = (b, hs: 64-wide h slice), grid 1024, 4 waves:
//   waves 0..2 = producers (one weight each, 64t x 64h, acc[4][4]);
//   wave 3 = consumer (64 chains, scans 64 t-steps/phase from P buf p&1).
// LDS: P dbuf 48KB + A 32KB = 80KB -> 2 blocks/CU. 8 phases, 2 barriers each.
__global__ void __launch_bounds__(256, 2) brc_fused(
    const f16* __restrict__ Af, const f16* __restrict__ Bf,
    const float* __restrict__ h0, const float* __restrict__ mr,
    const float* __restrict__ mz, const float* __restrict__ br,
    const float* __restrict__ bz, float* __restrict__ out) {
  __shared__ __align__(16) f16 Pl[2][12288];     // [buf][w*4096+tg*512+hl*8+t7]
  __shared__ __align__(16) f16 Al[16384];        // 32KB: phase A slice, frag order
  const int tid = threadIdx.x;
  const int wid = tid >> 6, lane = tid & 63;
  const int bid = blockIdx.x;
  const int lid = (bid & 7) * 128 + (bid >> 3);  // bijective XCD swizzle
  const int b = lid >> 3, hs = lid & 7;          // 8 hs-blocks of a b adjacent

  // ---- producer constants (waves 0..2): weight w3 = wid ----
  const int w3 = wid < 3 ? wid : 0;
  const char* Bp = (const char*)Bf + (lane >> 4) * 1024 + (lane & 15) * 16 +
                   (size_t)(hs * 3 + w3) * 32768;
  const int col = lane & 15, rbase = (lane >> 4) * 4;

  // ---- consumer state (wave 3): chain = lane ----
  float h = 0.f, mrc = 0.f, mzc = 0.f, br2 = 0.f, nbz = 0.f;
  if (wid == 3) {
    int hg = hs * 64 + lane;
    h = h0[(size_t)b * 512 + hg];
    mrc = 2.0f * mr[hg]; mzc = -mz[hg];
    br2 = 2.0f * br[hg]; nbz = -bz[hg];
  }

  // ---- persistent B: whole slice in registers, loaded once ----
  f16x8 breg[32];                                // [kt*4+ni], static indexing only
  if (wid < 3) {
#pragma unroll
    for (int kt = 0; kt < 8; ++kt)
#pragma unroll
      for (int ni = 0; ni < 4; ++ni)
        breg[kt * 4 + ni] = *(const f16x8*)(Bp + (size_t)kt * 4096 + ni * 256);
  }

  // stage phase q's A slice: frags (b*32+q*4+mi)*8+kt = 32 contiguous 1KB
  // chunks; producer waves round-robin (11/11/10 chunks).
#define STAGEA(q)                                                             \
  do {                                                                        \
    const char* gsrc = (const char*)Af + ((size_t)(b * 32 + (q) * 4) * 8) * 1024; \
    for (int j = wid; j < 32; j += 3)                                         \
      gload_lds16(gsrc + (size_t)j * 1024 + lane * 16, (char*)Al + j * 1024); \
  } while (0)

  auto gemm_phase = [&](int q) {
    f16* Pb = Pl[q & 1];
    f32x4 acc[4][4] = {};
#pragma unroll
    for (int kt = 0; kt < 8; ++kt) {
      f16x8 a[4];
#pragma unroll
      for (int mi = 0; mi < 4; ++mi)
        a[mi] = *(const f16x8*)((const char*)Al + (mi * 8 + kt) * 1024 + lane * 16);
#pragma unroll
      for (int mi = 0; mi < 4; ++mi)
#pragma unroll
        for (int ni = 0; ni < 4; ++ni)
          acc[mi][ni] = __builtin_amdgcn_mfma_f32_16x16x32_f16(
              a[mi], breg[kt * 4 + ni], acc[mi][ni], 0, 0, 0);
    }
#pragma unroll
    for (int mi = 0; mi < 4; ++mi) {
      int tl = mi * 16 + rbase;                  // 0..63
#pragma unroll
      for (int ni = 0; ni < 4; ++ni) {
        int hl = ni * 16 + col;                  // 0..63
        f16x4 v;
#pragma unroll
        for (int r = 0; r < 4; ++r) v[r] = (f16)acc[mi][ni][r];
        *(f16x4*)&Pb[w3 * 4096 + (tl >> 3) * 512 + hl * 8 + (tl & 7)] = v;
      }
    }
  };

  if (wid < 3) STAGEA(0);
  __syncthreads();                               // A0 landed
  if (wid < 3) gemm_phase(0);                    // prologue

  for (int p = 0; p < 8; ++p) {
    __syncthreads();                             // P[p&1] ready; A[p] dead
    if (wid < 3 && p + 1 < 8) STAGEA(p + 1);
    __syncthreads();                             // A[p+1] landed
    if (wid < 3) {
      if (p + 1 < 8) gemm_phase(p + 1);
    } else {
      const f16* Pb = Pl[p & 1];
      float* opm = out + ((size_t)b * 512 + p * 64) * 512 + hs * 64 + lane;
#pragma unroll
      for (int tg = 0; tg < 8; ++tg) {
        f16x8 R  = *(const f16x8*)&Pb[tg * 512 + lane * 8];
        f16x8 Z  = *(const f16x8*)&Pb[4096 + tg * 512 + lane * 8];
        f16x8 Hh = *(const f16x8*)&Pb[8192 + tg * 512 + lane * 8];
#pragma unroll
        for (int j = 0; j < 8; ++j) {
          float prs = fmaf((float)R[j], 2.0f, br2);
          float pzs = fmaf((float)Z[j], -1.0f, nbz);
          float ph2 = (float)Hh[j] * 2.0f;
          float er = __expf(fmaf(h, mrc, prs));
          float rr = fmaf(-2.0f, rcpf(er + 1.0f), 2.0f);
          float ez = __expf(fmaf(h, mzc, pzs));
          float zz = rcpf(1.0f + ez);
          float ec = __expf(fmaf(rr, h + h, ph2));
          float cd = fmaf(-2.0f, rcpf(ec + 1.0f), 1.0f);
          h = fmaf(zz, h - cd, cd);
          __builtin_nontemporal_store(h, opm + (size_t)(tg * 8 + j) * 512);
        }
      }
    }
  }
#undef STAGEA
}

// ---------------- launch ----------------
extern "C" void kernel_launch(void* const* d_in, const int* in_sizes, int n_in,
                              void* d_out, int out_size, void* d_ws, size_t ws_size,
                              hipStream_t stream) {
  const float* x  = (const float*)d_in[0];
  const float* h0 = (const float*)d_in[1];
  const float* kr = (const float*)d_in[2];
  const float* kz = (const float*)d_in[3];
  const float* kh = (const float*)d_in[4];
  const float* mr = (const float*)d_in[5];
  const float* mz = (const float*)d_in[6];
  const float* br = (const float*)d_in[7];
  const float* bz = (const float*)d_in[8];
  float* out = (float*)d_out;

  f16* Bf = (f16*)d_ws;                 // 393216 halfs = 786 KB
  f16* Xf = Bf + 393216;                // 16.8M halfs = 33.5 MB

  cvt_w<<<192, 256, 0, stream>>>(kr, kz, kh, Bf);
  cvt_x<<<8192, 256, 0, stream>>>(x, Xf);
  brc_fused<<<1024, 256, 0, stream>>>(Xf, Bf, h0, mr, mz, br, bz, out);
}

// Round 21
// 108.442 us; speedup vs baseline: 1.2256x; 1.1237x over previous
//
#include <hip/hip_runtime.h>

typedef _Float16 f16;
typedef _Float16 f16x8 __attribute__((ext_vector_type(8)));
typedef _Float16 f16x4 __attribute__((ext_vector_type(4)));
typedef float f32x4 __attribute__((ext_vector_type(4)));

__device__ __forceinline__ float rcpf(float x) { return __builtin_amdgcn_rcpf(x); }

__device__ __forceinline__ void gload_lds16(const void* g, void* l) {
  __builtin_amdgcn_global_load_lds(
      (const __attribute__((address_space(1))) void*)g,
      (__attribute__((address_space(3))) void*)l, 16, 0, 0);
}

// ---------------- kernel 1: merged converts (one dispatch) ----------------
// blocks 0..191: weight convert -> fragment-ordered Wt'
// blocks 192..8383: x convert f32->f16 fragment-ordered Xf'
__global__ void __launch_bounds__(256) cvt_all(const float* __restrict__ x,
                                               const float* __restrict__ Wr,
                                               const float* __restrict__ Wz,
                                               const float* __restrict__ Wh,
                                               f16* __restrict__ Bf,
                                               f16* __restrict__ Xf) {
  if (blockIdx.x < 192) {
    int o = blockIdx.x * 256 + threadIdx.x;      // < 49152
    int rl = o & 15, ni = (o >> 4) & 3, kq = (o >> 6) & 3, kt = (o >> 8) & 7;
    int wnt = o >> 11;
    int w = wnt % 3, nt = wnt / 3;
    int n = nt * 64 + ni * 16 + rl;
    int k0 = kt * 32 + kq * 8;
    const float* W = (w == 0) ? Wr : ((w == 1) ? Wz : Wh);
    f16x8 v;
#pragma unroll
    for (int e = 0; e < 8; ++e) v[e] = (f16)W[(size_t)(k0 + e) * 512 + n];
    *(f16x8*)(Bf + (size_t)o * 8) = v;
  } else {
    int o = (blockIdx.x - 192) * 256 + threadIdx.x;   // < 2097152
    int rl = o & 15, kq = (o >> 4) & 3, kt = (o >> 6) & 7, m16 = o >> 9;
    const float* src = x + (size_t)(m16 * 16 + rl) * 256 + kt * 32 + kq * 8;
    f16x8 v;
#pragma unroll
    for (int e = 0; e < 8; ++e) v[e] = (f16)src[e];
    *(f16x8*)(Xf + (size_t)o * 8) = v;
  }
}

// ---------------- kernel 2: producer/consumer fused GEMM + scan ------------
// R17 structure (best: fused=96us, 52-64 VGPR no-spill) + A DOUBLE-BUFFER:
// stage A[p+1] into the other 16KB buffer at phase START; the phase-end
// __syncthreads (drains vmcnt anyway) lands after a full compute phase.
// Removes the second barrier per phase (33 -> 17) and the exposed A-landing
// stall. LDS: P dbuf 48KB + A dbuf 32KB = 80KB -> 2 blocks/CU.
// Waves 0..5 (producers): w3=wid>>1 (weight), hh=wid&1 (h-half), 32t x 64h,
//   acc[2][4]; B from global (phase-invariant slice, L2-resident).
// Waves 6,7 (consumers): 128 chains, scan 32 t-steps of phase p from P[p&1].
__global__ void __launch_bounds__(512, 4) brc_fused(
    const f16* __restrict__ Af, const f16* __restrict__ Bf,
    const float* __restrict__ h0, const float* __restrict__ mr,
    const float* __restrict__ mz, const float* __restrict__ br,
    const float* __restrict__ bz, float* __restrict__ out) {
  __shared__ __align__(16) f16 Pl[2][12288];     // [buf][w3*4096+tg*1024+hl*8+t7]
  __shared__ __align__(16) f16 Al[2][8192];      // 2 x 16KB A slices, frag order
  const int tid = threadIdx.x;
  const int wid = tid >> 6, lane = tid & 63;
  const int bid = blockIdx.x;
  const int lid = (bid & 7) * 64 + (bid >> 3);   // bijective XCD swizzle
  const int b = lid >> 2, hs = lid & 3;          // 4 hs-blocks of a b adjacent

  // ---- producer constants (waves 0..5) ----
  const int w3 = wid >> 1, hh = wid & 1;
  const int nt = hs * 2 + hh;
  const char* Bp = (const char*)Bf + (lane >> 4) * 1024 + (lane & 15) * 16 +
                   (size_t)(nt * 3 + w3) * 32768;
  const int col = lane & 15, rbase = (lane >> 4) * 4;

  // ---- consumer state (waves 6,7): chain c = tid & 127 ----
  const int c = tid & 127;
  const int hg = hs * 128 + c;
  float h = h0[(size_t)b * 512 + hg];
  const float mrc = 2.0f * mr[hg], mzc = -mz[hg];
  const float br2 = 2.0f * br[hg], nbz = -bz[hg];

  // stage phase q's A slice into buffer q&1: 16 contiguous 1KB chunks,
  // 6 producer waves round-robin.
#define STAGEA(q)                                                             \
  do {                                                                        \
    const char* gsrc = (const char*)Af + ((size_t)(b * 32 + (q) * 2) * 8) * 1024; \
    char* adst = (char*)Al + ((q) & 1) * 16384;                               \
    for (int j = wid; j < 16; j += 6)                                         \
      gload_lds16(gsrc + (size_t)j * 1024 + lane * 16, adst + j * 1024);      \
  } while (0)

  auto gemm_phase = [&](int q) {
    f16* Pb = Pl[q & 1];
    const char* Ab = (const char*)Al + (q & 1) * 16384;
    f32x4 acc[2][4] = {};
#pragma unroll
    for (int kt = 0; kt < 8; ++kt) {
      f16x8 a[2], bfr[4];
#pragma unroll
      for (int mi = 0; mi < 2; ++mi)
        a[mi] = *(const f16x8*)(Ab + (mi * 8 + kt) * 1024 + lane * 16);
#pragma unroll
      for (int ni = 0; ni < 4; ++ni)
        bfr[ni] = *(const f16x8*)(Bp + (size_t)kt * 4096 + ni * 256);
#pragma unroll
      for (int mi = 0; mi < 2; ++mi)
#pragma unroll
        for (int ni = 0; ni < 4; ++ni)
          acc[mi][ni] = __builtin_amdgcn_mfma_f32_16x16x32_f16(
              a[mi], bfr[ni], acc[mi][ni], 0, 0, 0);
    }
#pragma unroll
    for (int mi = 0; mi < 2; ++mi) {
      int tl = mi * 16 + rbase;                  // 0..31
#pragma unroll
      for (int ni = 0; ni < 4; ++ni) {
        int hl = hh * 64 + ni * 16 + col;        // 0..127
        f16x4 v;
#pragma unroll
        for (int r = 0; r < 4; ++r) v[r] = (f16)acc[mi][ni][r];
        *(f16x4*)&Pb[w3 * 4096 + (tl >> 3) * 1024 + hl * 8 + (tl & 7)] = v;
      }
    }
  };

  if (wid < 6) STAGEA(0);
  __syncthreads();                               // A0 landed
  if (wid < 6) {
    STAGEA(1);                                   // async; lands by next barrier
    gemm_phase(0);                               // prologue -> P[0]
  }

  for (int p = 0; p < 16; ++p) {
    __syncthreads();   // P[p&1] ready; A[p+1] landed; prev scan done
    if (wid < 6) {
      if (p + 2 < 16) STAGEA(p + 2);             // into buf (p+2)&1 (A[p] dead)
      if (p + 1 < 16) gemm_phase(p + 1);         // reads A[p+1], writes P[(p+1)&1]
    } else {
      const f16* Pr_ = &Pl[p & 1][c * 8];
      const f16* Pz_ = Pr_ + 4096;
      const f16* Ph_ = Pr_ + 8192;
      float* opm = out + ((size_t)b * 512 + p * 32) * 512 + hg;
#pragma unroll
      for (int g = 0; g < 4; ++g) {
        f16x8 R  = *(const f16x8*)(Pr_ + g * 1024);
        f16x8 Z  = *(const f16x8*)(Pz_ + g * 1024);
        f16x8 Hh = *(const f16x8*)(Ph_ + g * 1024);
#pragma unroll
        for (int j = 0; j < 8; ++j) {
          float prs = fmaf((float)R[j], 2.0f, br2);
          float pzs = fmaf((float)Z[j], -1.0f, nbz);
          float ph2 = (float)Hh[j] * 2.0f;
          float er = __expf(fmaf(h, mrc, prs));
          float rr = fmaf(-2.0f, rcpf(er + 1.0f), 2.0f);
          float ez = __expf(fmaf(h, mzc, pzs));
          float zz = rcpf(1.0f + ez);
          float ec = __expf(fmaf(rr, h + h, ph2));
          float cd = fmaf(-2.0f, rcpf(ec + 1.0f), 1.0f);
          h = fmaf(zz, h - cd, cd);
          __builtin_nontemporal_store(h, opm + (size_t)(g * 8 + j) * 512);
        }
      }
    }
  }
#undef STAGEA
}

// ---------------- launch ----------------
extern "C" void kernel_launch(void* const* d_in, const int* in_sizes, int n_in,
                              void* d_out, int out_size, void* d_ws, size_t ws_size,
                              hipStream_t stream) {
  const float* x  = (const float*)d_in[0];
  const float* h0 = (const float*)d_in[1];
  const float* kr = (const float*)d_in[2];
  const float* kz = (const float*)d_in[3];
  const float* kh = (const float*)d_in[4];
  const float* mr = (const float*)d_in[5];
  const float* mz = (const float*)d_in[6];
  const float* br = (const float*)d_in[7];
  const float* bz = (const float*)d_in[8];
  float* out = (float*)d_out;

  f16* Bf = (f16*)d_ws;                 // 393216 halfs = 786 KB
  f16* Xf = Bf + 393216;                // 16.8M halfs = 33.5 MB

  cvt_all<<<8384, 256, 0, stream>>>(x, kr, kz, kh, Bf, Xf);
  brc_fused<<<512, 512, 0, stream>>>(Xf, Bf, h0, mr, mz, br, bz, out);
}

// Round 22
// 107.620 us; speedup vs baseline: 1.2350x; 1.0076x over previous
//
#include <hip/hip_runtime.h>

typedef _Float16 f16;
typedef _Float16 f16x8 __attribute__((ext_vector_type(8)));
typedef _Float16 f16x4 __attribute__((ext_vector_type(4)));
typedef float f32x4 __attribute__((ext_vector_type(4)));

__device__ __forceinline__ float rcpf(float x) { return __builtin_amdgcn_rcpf(x); }
__device__ __forceinline__ float exp2f_(float x) { return __builtin_amdgcn_exp2f(x); }

__device__ __forceinline__ void gload_lds16(const void* g, void* l) {
  __builtin_amdgcn_global_load_lds(
      (const __attribute__((address_space(1))) void*)g,
      (__attribute__((address_space(3))) void*)l, 16, 0, 0);
}

#define LOG2E 1.4426950408889634f

// ---------------- kernel 1: merged converts (one dispatch) ----------------
// blocks 0..191: weight convert -> fragment-ordered Wt'
// blocks 192..8383: x convert f32->f16 fragment-ordered Xf'
__global__ void __launch_bounds__(256) cvt_all(const float* __restrict__ x,
                                               const float* __restrict__ Wr,
                                               const float* __restrict__ Wz,
                                               const float* __restrict__ Wh,
                                               f16* __restrict__ Bf,
                                               f16* __restrict__ Xf) {
  if (blockIdx.x < 192) {
    int o = blockIdx.x * 256 + threadIdx.x;      // < 49152
    int rl = o & 15, ni = (o >> 4) & 3, kq = (o >> 6) & 3, kt = (o >> 8) & 7;
    int wnt = o >> 11;
    int w = wnt % 3, nt = wnt / 3;
    int n = nt * 64 + ni * 16 + rl;
    int k0 = kt * 32 + kq * 8;
    const float* W = (w == 0) ? Wr : ((w == 1) ? Wz : Wh);
    f16x8 v;
#pragma unroll
    for (int e = 0; e < 8; ++e) v[e] = (f16)W[(size_t)(k0 + e) * 512 + n];
    *(f16x8*)(Bf + (size_t)o * 8) = v;
  } else {
    int o = (blockIdx.x - 192) * 256 + threadIdx.x;   // < 2097152
    int rl = o & 15, kq = (o >> 4) & 3, kt = (o >> 6) & 7, m16 = o >> 9;
    const float* src = x + (size_t)(m16 * 16 + rl) * 256 + kt * 32 + kq * 8;
    f16x8 v;
#pragma unroll
    for (int e = 0; e < 8; ++e) v[e] = (f16)src[e];
    *(f16x8*)(Xf + (size_t)o * 8) = v;
  }
}

// ---------------- kernel 2: producer/consumer fused GEMM + scan ------------
// R21 structure (best) + (a) T5 setprio around the producer MFMA region
// (true role-split schedule: the regime where setprio measurably pays),
// (b) consumer scan in exp2 form with log2e pre-folded into all gate
// constants (removes 3 dependent v_mul from every serial t-step).
// Waves 0..5 (producers): w3=wid>>1 (weight), hh=wid&1 (h-half), 32t x 64h,
//   acc[2][4]; B from global (phase-invariant slice, L2-resident);
//   A via double-buffered 16KB LDS slices staged by global_load_lds.
// Waves 6,7 (consumers): 128 chains, scan 32 t-steps of phase p from P[p&1].
// LDS: P dbuf 48KB + A dbuf 32KB = 80KB -> 2 blocks/CU. 17 barriers total.
__global__ void __launch_bounds__(512, 4) brc_fused(
    const f16* __restrict__ Af, const f16* __restrict__ Bf,
    const float* __restrict__ h0, const float* __restrict__ mr,
    const float* __restrict__ mz, const float* __restrict__ br,
    const float* __restrict__ bz, float* __restrict__ out) {
  __shared__ __align__(16) f16 Pl[2][12288];     // [buf][w3*4096+tg*1024+hl*8+t7]
  __shared__ __align__(16) f16 Al[2][8192];      // 2 x 16KB A slices, frag order
  const int tid = threadIdx.x;
  const int wid = tid >> 6, lane = tid & 63;
  const int bid = blockIdx.x;
  const int lid = (bid & 7) * 64 + (bid >> 3);   // bijective XCD swizzle
  const int b = lid >> 2, hs = lid & 3;          // 4 hs-blocks of a b adjacent

  // ---- producer constants (waves 0..5) ----
  const int w3 = wid >> 1, hh = wid & 1;
  const int nt = hs * 2 + hh;
  const char* Bp = (const char*)Bf + (lane >> 4) * 1024 + (lane & 15) * 16 +
                   (size_t)(nt * 3 + w3) * 32768;
  const int col = lane & 15, rbase = (lane >> 4) * 4;

  // ---- consumer state (waves 6,7): chain c = tid & 127 ----
  // exp2 form: r: e=exp2(fma(h,mrcL, fma(R,2L,brL))); z: e=exp2(fma(h,mzL, fma(Z,-L,bzL)))
  // c: e=exp2(fma(rr, h*2L, Hh*2L))
  const int c = tid & 127;
  const int hg = hs * 128 + c;
  float h = h0[(size_t)b * 512 + hg];
  const float mrcL = 2.0f * LOG2E * mr[hg], mzL = -LOG2E * mz[hg];
  const float brL = 2.0f * LOG2E * br[hg], bzL = -LOG2E * bz[hg];

  // stage phase q's A slice into buffer q&1: 16 contiguous 1KB chunks,
  // 6 producer waves round-robin.
#define STAGEA(q)                                                             \
  do {                                                                        \
    const char* gsrc = (const char*)Af + ((size_t)(b * 32 + (q) * 2) * 8) * 1024; \
    char* adst = (char*)Al + ((q) & 1) * 16384;                               \
    for (int j = wid; j < 16; j += 6)                                         \
      gload_lds16(gsrc + (size_t)j * 1024 + lane * 16, adst + j * 1024);      \
  } while (0)

  auto gemm_phase = [&](int q) {
    f16* Pb = Pl[q & 1];
    const char* Ab = (const char*)Al + (q & 1) * 16384;
    f32x4 acc[2][4] = {};
    __builtin_amdgcn_s_setprio(1);               // T5: favor producer waves
#pragma unroll
    for (int kt = 0; kt < 8; ++kt) {
      f16x8 a[2], bfr[4];
#pragma unroll
      for (int mi = 0; mi < 2; ++mi)
        a[mi] = *(const f16x8*)(Ab + (mi * 8 + kt) * 1024 + lane * 16);
#pragma unroll
      for (int ni = 0; ni < 4; ++ni)
        bfr[ni] = *(const f16x8*)(Bp + (size_t)kt * 4096 + ni * 256);
#pragma unroll
      for (int mi = 0; mi < 2; ++mi)
#pragma unroll
        for (int ni = 0; ni < 4; ++ni)
          acc[mi][ni] = __builtin_amdgcn_mfma_f32_16x16x32_f16(
              a[mi], bfr[ni], acc[mi][ni], 0, 0, 0);
    }
    __builtin_amdgcn_s_setprio(0);
#pragma unroll
    for (int mi = 0; mi < 2; ++mi) {
      int tl = mi * 16 + rbase;                  // 0..31
#pragma unroll
      for (int ni = 0; ni < 4; ++ni) {
        int hl = hh * 64 + ni * 16 + col;        // 0..127
        f16x4 v;
#pragma unroll
        for (int r = 0; r < 4; ++r) v[r] = (f16)acc[mi][ni][r];
        *(f16x4*)&Pb[w3 * 4096 + (tl >> 3) * 1024 + hl * 8 + (tl & 7)] = v;
      }
    }
  };

  if (wid < 6) STAGEA(0);
  __syncthreads();                               // A0 landed
  if (wid < 6) {
    STAGEA(1);                                   // async; lands by next barrier
    gemm_phase(0);                               // prologue -> P[0]
  }

  for (int p = 0; p < 16; ++p) {
    __syncthreads();   // P[p&1] ready; A[p+1] landed; prev scan done
    if (wid < 6) {
      if (p + 2 < 16) STAGEA(p + 2);             // into buf (p+2)&1 (A[p] dead)
      if (p + 1 < 16) gemm_phase(p + 1);         // reads A[p+1], writes P[(p+1)&1]
    } else {
      const f16* Pr_ = &Pl[p & 1][c * 8];
      const f16* Pz_ = Pr_ + 4096;
      const f16* Ph_ = Pr_ + 8192;
      float* opm = out + ((size_t)b * 512 + p * 32) * 512 + hg;
#pragma unroll
      for (int g = 0; g < 4; ++g) {
        f16x8 R  = *(const f16x8*)(Pr_ + g * 1024);
        f16x8 Z  = *(const f16x8*)(Pz_ + g * 1024);
        f16x8 Hh = *(const f16x8*)(Ph_ + g * 1024);
#pragma unroll
        for (int j = 0; j < 8; ++j) {
          float prs = fmaf((float)R[j], 2.0f * LOG2E, brL);
          float pzs = fmaf((float)Z[j], -LOG2E, bzL);
          float phL = (float)Hh[j] * (2.0f * LOG2E);
          float er = exp2f_(fmaf(h, mrcL, prs));
          float rr = fmaf(-2.0f, rcpf(er + 1.0f), 2.0f);
          float ez = exp2f_(fmaf(h, mzL, pzs));
          float zz = rcpf(1.0f + ez);
          float h2L = h * (2.0f * LOG2E);
          float ec = exp2f_(fmaf(rr, h2L, phL));
          float cd = fmaf(-2.0f, rcpf(ec + 1.0f), 1.0f);
          h = fmaf(zz, h - cd, cd);
          __builtin_nontemporal_store(h, opm + (size_t)(g * 8 + j) * 512);
        }
      }
    }
  }
#undef STAGEA
}

// ---------------- launch ----------------
extern "C" void kernel_launch(void* const* d_in, const int* in_sizes, int n_in,
                              void* d_out, int out_size, void* d_ws, size_t ws_size,
                              hipStream_t stream) {
  const float* x  = (const float*)d_in[0];
  const float* h0 = (const float*)d_in[1];
  const float* kr = (const float*)d_in[2];
  const float* kz = (const float*)d_in[3];
  const float* kh = (const float*)d_in[4];
  const float* mr = (const float*)d_in[5];
  const float* mz = (const float*)d_in[6];
  const float* br = (const float*)d_in[7];
  const float* bz = (const float*)d_in[8];
  float* out = (float*)d_out;

  f16* Bf = (f16*)d_ws;                 // 393216 halfs = 786 KB
  f16* Xf = Bf + 393216;                // 16.8M halfs = 33.5 MB

  cvt_all<<<8384, 256, 0, stream>>>(x, kr, kz, kh, Bf, Xf);
  brc_fused<<<512, 512, 0, stream>>>(Xf, Bf, h0, mr, mz, br, bz, out);
}